// Round 8
// baseline (885.142 us; speedup 1.0000x reference)
//
#include <hip/hip_runtime.h>
#include <math.h>

#define N 4096
#define DD 256
#define CAP 512      // per-column candidate capacity (~224 expected, 128-row slabs)
#define RCAP 256     // per-row candidate capacity (tau + beta gather)
#define SCAP 48      // per-(column,unit) LDS staging slots (overflow -> direct)
#define LEAKY 0.2f
#define NBLK 512     // 512 blocks x 256 thr = exactly 2 blocks/CU on 256 CUs

typedef float v4f __attribute__((ext_vector_type(4)));

__device__ __forceinline__ void nt_store4(const float4& p, float4* dst){
  v4f v = { p.x, p.y, p.z, p.w };
  __builtin_nontemporal_store(v, (v4f*)dst);
}

// Device-scope grid barrier (manual cooperative). All blocks are co-resident
// by construction (launch_bounds(256,2), 17.7KB LDS -> 2 blocks/CU * 256 CU
// = 512 = grid). threadfence = agent scope: L2 writeback + inv, so data
// written before the barrier is visible across XCDs after it.
__device__ __forceinline__ void gbar(int* bar, int slot){
  __threadfence();
  __syncthreads();
  if (threadIdx.x == 0){
    __hip_atomic_fetch_add(&bar[slot], 1, __ATOMIC_RELEASE, __HIP_MEMORY_SCOPE_AGENT);
    while (__hip_atomic_load(&bar[slot], __ATOMIC_ACQUIRE, __HIP_MEMORY_SCOPE_AGENT) < NBLK)
      __builtin_amdgcn_s_sleep(2);
  }
  __syncthreads();
  __threadfence();
}

// ---------------------------------------------------------------------------
// Whole pipeline, ONE kernel, phases verbatim from the round-7 PASSED kernels:
//  P1 column candidates (2048 units: coalesced loads, LDS-staged float2 stores)
//  P2 column tau Michelot + alpha gather (1024 units)
//  P3 row sparsemax per-wave + out_row/out_col + beta gather (1024 units)
//  P4 G(x)=leaky(x@W+b) column-sum reduction (512 units)
//  P5 cosine scalar (redundant per block) + out0 fill (32 float4/thread)
// ---------------------------------------------------------------------------
__global__ __launch_bounds__(256, 2) void k_fused(
      const float* __restrict__ rowvecs, const float* __restrict__ colvecs,
      const float* __restrict__ cost, const float* __restrict__ W,
      const float* __restrict__ bG,
      float* __restrict__ out0, float* __restrict__ out_row,
      float* __restrict__ out_col,
      int* __restrict__ cnt, float* __restrict__ vsum, int* __restrict__ bar,
      float* __restrict__ tau_col, float* __restrict__ beta,
      float* __restrict__ alpha, float2* __restrict__ candp)
{
  const int bid = blockIdx.x;
  const int t = threadIdx.x, w = t >> 6, lane = t & 63;
  __shared__ __align__(16) unsigned char smem[17664];

  // ------------------- P1: column candidates -------------------
  {
    float (*smax)[64] = (float (*)[64])smem;                       // 1 KB
    int   (*scnt)[64] = (int   (*)[64])(smem + 1024);              // 1 KB
    int*   sbase      = (int*)(smem + 2048);                       // 256 B
    float (*sval)[SCAP] = (float (*)[SCAP])(smem + 2304);          // 12 KB
    unsigned char (*sidx)[SCAP] =
        (unsigned char (*)[SCAP])(smem + 2304 + 12288);            // 3 KB
    const int tc = t & 63, tr = t >> 6;
    for (int u = bid; u < 2048; u += NBLK){
      const int j  = (u & 63) * 64 + tc;
      const int r0 = (u >> 6) * 128;
      const float* p = cost + (size_t)(r0 + tr * 32) * N + j;

      float v[32];
      #pragma unroll
      for (int r = 0; r < 32; ++r) v[r] = -p[(size_t)r * N];

      float m = v[0];
      #pragma unroll
      for (int r = 1; r < 32; ++r) m = fmaxf(m, v[r]);

      smax[tr][tc] = m;
      __syncthreads();
      const float m4 = fmaxf(fmaxf(smax[0][tc], smax[1][tc]),
                             fmaxf(smax[2][tc], smax[3][tc]));
      const float th = m4 - 1.0f;

      int nc = 0;
      #pragma unroll
      for (int r = 0; r < 32; ++r) nc += (v[r] > th) ? 1 : 0;
      scnt[tr][tc] = nc;
      __syncthreads();

      int myoff = 0;
      #pragma unroll
      for (int s = 0; s < 4; ++s) if (s < tr) myoff += scnt[s][tc];
      const int tot = scnt[0][tc] + scnt[1][tc] + scnt[2][tc] + scnt[3][tc];

      if (tr == 0) sbase[tc] = atomicAdd(&cnt[j], tot);  // 1 atomic/(col,unit)
      __syncthreads();
      const int b = sbase[tc];

      int pos = myoff;
      #pragma unroll
      for (int r = 0; r < 32; ++r){
        if (v[r] > th){
          if (pos < SCAP){
            sval[tc][pos] = v[r];
            sidx[tc][pos] = (unsigned char)(tr * 32 + r);
          } else {
            int q = b + pos;
            if (q < CAP)
              candp[(size_t)j * CAP + q] =
                  make_float2(v[r], __int_as_float(r0 + tr * 32 + r));
          }
          ++pos;
        }
      }
      __syncthreads();

      // coalesced write: 4 threads/column, 8 B pairs -> 32 B chunks
      const int lc = t >> 2;
      const int qq = t & 3;
      const int jj = (u & 63) * 64 + lc;
      const int cc = min(scnt[0][lc] + scnt[1][lc] + scnt[2][lc] + scnt[3][lc], SCAP);
      const int bb = sbase[lc];
      for (int s = qq; s < cc; s += 4){
        int q = bb + s;
        if (q < CAP)
          candp[(size_t)jj * CAP + q] =
              make_float2(sval[lc][s], __int_as_float(r0 + (int)sidx[lc][s]));
      }
      __syncthreads();   // protect LDS reuse next unit
    }
  }
  gbar(bar, 0);

  // ------------------- P2: column tau + alpha -------------------
  {
    float (*sup_v)[CAP] = (float (*)[CAP])smem;            // 8 KB
    int   (*sup_i)[CAP] = (int   (*)[CAP])(smem + 8192);   // 8 KB
    for (int u = bid; u < 1024; u += NBLK){
      const int j = u * 4 + w;
      const int c = min(cnt[j], CAP);
      const float2* cp = candp + (size_t)j * CAP;

      float v[8]; int id[8];
      #pragma unroll
      for (int s = 0; s < 8; ++s){
        int l = s * 64 + lane;
        float2 pr = (l < c) ? cp[l] : make_float2(-3.4e38f, 0.0f);
        v[s]  = pr.x;
        id[s] = __float_as_int(pr.y);
      }

      float tau = -3.0e38f;
      for (int it = 0; it < 40; ++it){
        float sum = 0.0f, cf = 0.0f;
        #pragma unroll
        for (int s = 0; s < 8; ++s) if (v[s] > tau){ sum += v[s]; cf += 1.0f; }
        for (int off = 32; off; off >>= 1){ sum += __shfl_xor(sum, off); cf += __shfl_xor(cf, off); }
        float nt = (sum - 1.0f) / cf;
        if (nt == tau) break;
        tau = nt;
      }
      if (lane == 0) tau_col[j] = tau;

      int base = 0;
      #pragma unroll
      for (int s = 0; s < 8; ++s){
        bool pred = (v[s] > tau);
        unsigned long long mk = __ballot(pred);
        if (pred){
          int pos = base + __popcll(mk & ((1ULL << lane) - 1ULL));
          sup_v[w][pos] = v[s] - tau;
          sup_i[w][pos] = id[s];
        }
        base += __popcll(mk);
      }
      const int ns = base;
      __builtin_amdgcn_wave_barrier();
      __asm__ volatile("s_waitcnt lgkmcnt(0)");

      float a0 = 0, a1 = 0, a2 = 0, a3 = 0;
      #pragma unroll 4
      for (int l = 0; l < ns; ++l){
        float pp = sup_v[w][l];
        const float* ar = rowvecs + (size_t)sup_i[w][l] * DD;
        a0 += pp * ar[lane];        a1 += pp * ar[64 + lane];
        a2 += pp * ar[128 + lane];  a3 += pp * ar[192 + lane];
      }
      float* al = alpha + (size_t)j * DD;
      al[lane] = a0; al[64 + lane] = a1; al[128 + lane] = a2; al[192 + lane] = a3;
    }
  }
  gbar(bar, 1);

  // ------------------- P3: row sparsemax + outputs + beta -------------------
  {
    float (*sup_v)[RCAP] = (float (*)[RCAP])smem;           // 4 KB
    int   (*sup_j)[RCAP] = (int   (*)[RCAP])(smem + 4096);  // 4 KB
    const float4* tau4 = (const float4*)tau_col;
    for (int u = bid; u < 1024; u += NBLK){
      const int i = u * 4 + w;
      const float4* row4 = (const float4*)(cost + (size_t)i * N);
      float4 x4[16];
      #pragma unroll
      for (int s = 0; s < 16; ++s){
        float4 v = row4[lane + s * 64];
        x4[s] = make_float4(-v.x, -v.y, -v.z, -v.w);
      }

      float m = -3.4e38f;
      #pragma unroll
      for (int s = 0; s < 16; ++s)
        m = fmaxf(m, fmaxf(fmaxf(x4[s].x, x4[s].y), fmaxf(x4[s].z, x4[s].w)));
      #pragma unroll
      for (int off = 32; off; off >>= 1) m = fmaxf(m, __shfl_xor(m, off));
      const float th = m - 1.0f;

      int base = 0;
      #pragma unroll
      for (int s = 0; s < 16; ++s){
        const float* e = &x4[s].x;
        int jb = 4 * (lane + s * 64);
        #pragma unroll
        for (int c = 0; c < 4; ++c){
          bool pred = (e[c] > th);
          unsigned long long mk = __ballot(pred);
          if (pred){
            int pos = base + __popcll(mk & ((1ULL << lane) - 1ULL));
            if (pos < RCAP){ sup_v[w][pos] = e[c]; sup_j[w][pos] = jb + c; }
          }
          base += __popcll(mk);
        }
      }
      const int ns = min(base, RCAP);
      __builtin_amdgcn_wave_barrier();
      __asm__ volatile("s_waitcnt lgkmcnt(0)");

      float cv[4];
      #pragma unroll
      for (int s = 0; s < 4; ++s){
        int l = s * 64 + lane;
        cv[s] = (l < ns) ? sup_v[w][l] : -3.4e38f;
      }
      float tau = th;
      for (int it = 0; it < 40; ++it){
        float sum = 0.0f, cf = 0.0f;
        #pragma unroll
        for (int s = 0; s < 4; ++s) if (cv[s] > tau){ sum += cv[s]; cf += 1.0f; }
        for (int off = 32; off; off >>= 1){ sum += __shfl_xor(sum, off); cf += __shfl_xor(cf, off); }
        float nt = (sum - 1.0f) / cf;
        if (nt == tau) break;
        tau = nt;
      }

      float4* orow4 = (float4*)(out_row + (size_t)i * N);
      float4* ocol4 = (float4*)(out_col + (size_t)i * N);
      #pragma unroll
      for (int s = 0; s < 16; ++s){
        float4 p;
        p.x = fmaxf(x4[s].x - tau, 0.0f);
        p.y = fmaxf(x4[s].y - tau, 0.0f);
        p.z = fmaxf(x4[s].z - tau, 0.0f);
        p.w = fmaxf(x4[s].w - tau, 0.0f);
        nt_store4(p, &orow4[lane + s * 64]);

        float4 tt = tau4[lane + s * 64];
        float4 pc;
        pc.x = fmaxf(x4[s].x - tt.x, 0.0f);
        pc.y = fmaxf(x4[s].y - tt.y, 0.0f);
        pc.z = fmaxf(x4[s].z - tt.z, 0.0f);
        pc.w = fmaxf(x4[s].w - tt.w, 0.0f);
        nt_store4(pc, &ocol4[lane + s * 64]);
      }

      float a0 = 0, a1 = 0, a2 = 0, a3 = 0;
      for (int l = 0; l < ns; ++l){
        float pp = sup_v[w][l] - tau;
        if (pp > 0.0f){
          const float* cr = colvecs + (size_t)sup_j[w][l] * DD;
          a0 += pp * cr[lane];        a1 += pp * cr[64 + lane];
          a2 += pp * cr[128 + lane];  a3 += pp * cr[192 + lane];
        }
      }
      float* be = beta + (size_t)i * DD;
      be[lane] = a0; be[64 + lane] = a1; be[128 + lane] = a2; be[192 + lane] = a3;
    }
  }
  gbar(bar, 2);

  // ------------------- P4: G + column-sum reduction (512 units) -------------
  {
    float* sB = (float*)smem;                  // 16 KB
    const int side = bid >> 8;                 // 0: beta, 1: alpha
    const int r0   = (bid & 255) * 16;
    const float* src = side ? alpha : beta;
    #pragma unroll
    for (int k = 0; k < 16; ++k) sB[k * 256 + t] = src[(size_t)(r0 + k) * 256 + t];
    __syncthreads();
    float acc[16];
    float bg = bG[t];
    #pragma unroll
    for (int r = 0; r < 16; ++r) acc[r] = bg;
    const float4* sB4 = (const float4*)sB;
    for (int d4 = 0; d4 < 64; ++d4){
      int d = d4 * 4;
      float w0 = W[(size_t)d * 256 + t];
      float w1 = W[(size_t)(d + 1) * 256 + t];
      float w2 = W[(size_t)(d + 2) * 256 + t];
      float w3 = W[(size_t)(d + 3) * 256 + t];
      #pragma unroll
      for (int r = 0; r < 16; ++r){
        float4 s = sB4[r * 64 + d4];
        acc[r] += s.x * w0 + s.y * w1 + s.z * w2 + s.w * w3;
      }
    }
    float s = 0.0f;
    #pragma unroll
    for (int r = 0; r < 16; ++r){ float u = acc[r]; s += (u > 0.0f) ? u : LEAKY * u; }
    atomicAdd(&vsum[side * 256 + t], s);
  }
  gbar(bar, 3);

  // ------------------- P5: cosine scalar + out0 fill -------------------
  {
    float* rd = (float*)smem;   // 13 floats
    float v1 = vsum[t]       * (1.0f / 4096.0f);
    float v2 = vsum[256 + t] * (1.0f / 4096.0f);
    float d = v1 * v2, a = v1 * v1, b = v2 * v2;
    for (int off = 32; off; off >>= 1){
      d += __shfl_xor(d, off); a += __shfl_xor(a, off); b += __shfl_xor(b, off);
    }
    if (lane == 0){ rd[w] = d; rd[4 + w] = a; rd[8 + w] = b; }
    __syncthreads();
    if (t == 0){
      float dd = rd[0] + rd[1] + rd[2] + rd[3];
      float aa = rd[4] + rd[5] + rd[6] + rd[7];
      float bb = rd[8] + rd[9] + rd[10] + rd[11];
      rd[12] = 1.0f - dd / (sqrtf(aa) * sqrtf(bb) + 1e-8f);
    }
    __syncthreads();
    const float y = rd[12];
    const float4 f = make_float4(y, y, y, y);
    // out0 = 4,194,304 float4; /512 blocks = 8192/block = 32 per thread
    float4* o4 = (float4*)out0 + (size_t)bid * 8192;
    #pragma unroll
    for (int k = 0; k < 32; ++k) nt_store4(f, &o4[t + k * 256]);
  }
}

extern "C" void kernel_launch(void* const* d_in, const int* in_sizes, int n_in,
                              void* d_out, int out_size, void* d_ws, size_t ws_size,
                              hipStream_t stream){
  const float* rowv = (const float*)d_in[0];   // [4096,256]
  const float* colv = (const float*)d_in[1];   // [4096,256]
  const float* cost = (const float*)d_in[2];   // [4096,4096]
  const float* W    = (const float*)d_in[3];   // [256,256]
  const float* bG   = (const float*)d_in[4];   // [256]

  float* out0    = (float*)d_out;
  float* out_row = out0 + (size_t)N * N;
  float* out_col = out0 + 2 * (size_t)N * N;

  int*    cnt   = (int*)d_ws;                          // 4096 ints
  float*  vsum  = (float*)d_ws + 4096;                 // 512 floats
  int*    bar   = (int*)d_ws + 4608;                   // 16 ints
  float*  tau   = (float*)d_ws + 4624;                 // 4096 floats
  float*  beta  = (float*)d_ws + 16384;                // 1M floats
  float*  alpha = (float*)d_ws + 16384 + 1048576;      // 1M floats
  float2* candp = (float2*)((float*)d_ws + 16384 + 2 * 1048576);  // 16.8 MB

  // zero cnt + vsum + bar (barrier counters MUST be zero each replay)
  hipMemsetAsync(d_ws, 0, (size_t)4624 * 4, stream);

  void* args[] = { (void*)&rowv, (void*)&colv, (void*)&cost, (void*)&W,
                   (void*)&bG, (void*)&out0, (void*)&out_row, (void*)&out_col,
                   (void*)&cnt, (void*)&vsum, (void*)&bar, (void*)&tau,
                   (void*)&beta, (void*)&alpha, (void*)&candp };
  hipLaunchKernelGGL(k_fused, dim3(NBLK), dim3(256), 0, stream,
                     rowv, colv, cost, W, bG, out0, out_row, out_col,
                     cnt, vsum, bar, tau, beta, alpha, candp);
  (void)args;
}

// Round 10
// 335.518 us; speedup vs baseline: 2.6381x; 2.6381x over previous
//
#include <hip/hip_runtime.h>
#include <math.h>

#define N 4096
#define DD 256
#define CAP 512      // per-column candidate capacity (~224 expected, 128-row slabs)
#define RCAP 256     // per-row candidate capacity (tau + beta gather)
#define SCAP 48      // per-(column,unit) LDS staging slots (overflow -> direct)
#define LEAKY 0.2f

// ---------------------------------------------------------------------------
// Pass 1: column candidate compaction, COALESCED STORES. (verbatim round 7)
// Block = 256 thr = 64 cols x 4 row-chunks of 32 -> 128-row slab. Wave = 64
// consecutive columns of one row -> 256 B contiguous loads.
// th = m_slab - 1 <= M_j - 1 <= tau*_j  ==> candidate superset (exact).
// ---------------------------------------------------------------------------
__global__ __launch_bounds__(256) void k_cand(const float* __restrict__ cost,
      int* __restrict__ cnt, float2* __restrict__ candp){
  const int tc = threadIdx.x & 63;        // column within group (64)
  const int tr = threadIdx.x >> 6;        // row chunk (4 chunks of 32)
  const int j  = blockIdx.x * 64 + tc;
  const int r0 = blockIdx.y * 128;        // slab base row
  const float* p = cost + (size_t)(r0 + tr * 32) * N + j;

  float v[32];
  #pragma unroll
  for (int r = 0; r < 32; ++r) v[r] = -p[(size_t)r * N];

  float m = v[0];
  #pragma unroll
  for (int r = 1; r < 32; ++r) m = fmaxf(m, v[r]);

  __shared__ float smax[4][64];
  __shared__ int   scnt[4][64];
  __shared__ int   sbase[64];
  __shared__ float sval[64][SCAP];
  __shared__ unsigned char sidx[64][SCAP];

  smax[tr][tc] = m;
  __syncthreads();
  const float m4 = fmaxf(fmaxf(smax[0][tc], smax[1][tc]),
                         fmaxf(smax[2][tc], smax[3][tc]));
  const float th = m4 - 1.0f;

  int nc = 0;
  #pragma unroll
  for (int r = 0; r < 32; ++r) nc += (v[r] > th) ? 1 : 0;
  scnt[tr][tc] = nc;
  __syncthreads();

  int myoff = 0;
  #pragma unroll
  for (int s = 0; s < 4; ++s) if (s < tr) myoff += scnt[s][tc];
  const int tot = scnt[0][tc] + scnt[1][tc] + scnt[2][tc] + scnt[3][tc];

  if (tr == 0) sbase[tc] = atomicAdd(&cnt[j], tot);   // 1 atomic/(col,unit)
  __syncthreads();
  const int b = sbase[tc];

  // stage into LDS; overflow (pos >= SCAP) goes direct (rare)
  int pos = myoff;
  #pragma unroll
  for (int r = 0; r < 32; ++r){
    if (v[r] > th){
      if (pos < SCAP){
        sval[tc][pos] = v[r];
        sidx[tc][pos] = (unsigned char)(tr * 32 + r);
      } else {
        int q = b + pos;
        if (q < CAP)
          candp[(size_t)j * CAP + q] =
              make_float2(v[r], __int_as_float(r0 + tr * 32 + r));
      }
      ++pos;
    }
  }
  __syncthreads();

  // coalesced write phase: 4 threads per column, 8 B pairs -> 32 B chunks
  const int lc = threadIdx.x >> 2;        // local column 0..63
  const int qq = threadIdx.x & 3;
  const int jj = blockIdx.x * 64 + lc;
  const int cc = min(scnt[0][lc] + scnt[1][lc] + scnt[2][lc] + scnt[3][lc], SCAP);
  const int bb = sbase[lc];
  for (int s = qq; s < cc; s += 4){
    int q = bb + s;
    if (q < CAP)
      candp[(size_t)jj * CAP + q] =
          make_float2(sval[lc][s], __int_as_float(r0 + (int)sidx[lc][s]));
  }
}

// ---------------------------------------------------------------------------
// Column tau (Michelot on candidates, one wave per column) + alpha[j,:].
// (verbatim round 7)
// ---------------------------------------------------------------------------
__global__ __launch_bounds__(256) void k_coltau(const int* __restrict__ cnt,
      const float2* __restrict__ candp,
      const float* __restrict__ rowvecs, float* __restrict__ tau_out,
      float* __restrict__ alpha){
  const int t = threadIdx.x, w = t >> 6, lane = t & 63;
  const int j = blockIdx.x * 4 + w;
  const int c = min(cnt[j], CAP);
  const float2* cp = candp + (size_t)j * CAP;

  float v[8]; int id[8];
  #pragma unroll
  for (int s = 0; s < 8; ++s){
    int l = s * 64 + lane;
    float2 pr = (l < c) ? cp[l] : make_float2(-3.4e38f, 0.0f);
    v[s]  = pr.x;
    id[s] = __float_as_int(pr.y);
  }

  float tau = -3.0e38f;
  for (int it = 0; it < 40; ++it){
    float sum = 0.0f, cf = 0.0f;
    #pragma unroll
    for (int s = 0; s < 8; ++s) if (v[s] > tau){ sum += v[s]; cf += 1.0f; }
    for (int off = 32; off; off >>= 1){ sum += __shfl_xor(sum, off); cf += __shfl_xor(cf, off); }
    float nt = (sum - 1.0f) / cf;
    if (nt == tau) break;
    tau = nt;
  }
  if (lane == 0) tau_out[j] = tau;

  // compact support (v - tau > 0) into per-wave LDS
  __shared__ float sup_v[4][CAP];
  __shared__ int   sup_i[4][CAP];
  int base = 0;
  #pragma unroll
  for (int s = 0; s < 8; ++s){
    bool pred = (v[s] > tau);
    unsigned long long mk = __ballot(pred);
    if (pred){
      int pos = base + __popcll(mk & ((1ULL << lane) - 1ULL));
      sup_v[w][pos] = v[s] - tau;
      sup_i[w][pos] = id[s];
    }
    base += __popcll(mk);
  }
  const int ns = base;
  __builtin_amdgcn_wave_barrier();
  __asm__ volatile("s_waitcnt lgkmcnt(0)");

  float a0 = 0, a1 = 0, a2 = 0, a3 = 0;
  #pragma unroll 4
  for (int l = 0; l < ns; ++l){
    float pp = sup_v[w][l];
    const float* ar = rowvecs + (size_t)sup_i[w][l] * DD;
    a0 += pp * ar[lane];        a1 += pp * ar[64 + lane];
    a2 += pp * ar[128 + lane];  a3 += pp * ar[192 + lane];
  }
  float* al = alpha + (size_t)j * DD;
  al[lane] = a0; al[64 + lane] = a1; al[128 + lane] = a2; al[192 + lane] = a3;
}

// ---------------------------------------------------------------------------
// Row sparsemax, per-wave, candidate-compacted Michelot. (round 7 structure,
// but PLAIN stores: L3 absorbs the 134 MB write burst; cost stays resident.)
// ---------------------------------------------------------------------------
__global__ __launch_bounds__(256) void k_row(const float* __restrict__ cost,
      const float* __restrict__ colvecs, const float* __restrict__ tau_col,
      float* __restrict__ out_row, float* __restrict__ out_col,
      float* __restrict__ beta){
  const int t = threadIdx.x, w = t >> 6, lane = t & 63;
  const int i = blockIdx.x * 4 + w;
  __shared__ float sup_v[4][RCAP];
  __shared__ int   sup_j[4][RCAP];

  const float4* row4 = (const float4*)(cost + (size_t)i * N);
  float4 x4[16];
  #pragma unroll
  for (int s = 0; s < 16; ++s){
    float4 v = row4[lane + s * 64];
    x4[s] = make_float4(-v.x, -v.y, -v.z, -v.w);
  }

  float m = -3.4e38f;
  #pragma unroll
  for (int s = 0; s < 16; ++s)
    m = fmaxf(m, fmaxf(fmaxf(x4[s].x, x4[s].y), fmaxf(x4[s].z, x4[s].w)));
  #pragma unroll
  for (int off = 32; off; off >>= 1) m = fmaxf(m, __shfl_xor(m, off));
  const float th = m - 1.0f;

  // single ballot-compaction of candidates {v > M-1} (superset of support)
  int base = 0;
  #pragma unroll
  for (int s = 0; s < 16; ++s){
    const float* e = &x4[s].x;
    int jb = 4 * (lane + s * 64);
    #pragma unroll
    for (int c = 0; c < 4; ++c){
      bool pred = (e[c] > th);
      unsigned long long mk = __ballot(pred);
      if (pred){
        int pos = base + __popcll(mk & ((1ULL << lane) - 1ULL));
        if (pos < RCAP){ sup_v[w][pos] = e[c]; sup_j[w][pos] = jb + c; }
      }
      base += __popcll(mk);
    }
  }
  const int ns = min(base, RCAP);
  __builtin_amdgcn_wave_barrier();
  __asm__ volatile("s_waitcnt lgkmcnt(0)");

  // Michelot on the compacted set (4 regs/lane), tau0 = M-1 -> exact
  float cv[4];
  #pragma unroll
  for (int s = 0; s < 4; ++s){
    int l = s * 64 + lane;
    cv[s] = (l < ns) ? sup_v[w][l] : -3.4e38f;
  }
  float tau = th;
  for (int it = 0; it < 40; ++it){
    float sum = 0.0f, cf = 0.0f;
    #pragma unroll
    for (int s = 0; s < 4; ++s) if (cv[s] > tau){ sum += cv[s]; cf += 1.0f; }
    for (int off = 32; off; off >>= 1){ sum += __shfl_xor(sum, off); cf += __shfl_xor(cf, off); }
    float nt = (sum - 1.0f) / cf;
    if (nt == tau) break;
    tau = nt;
  }

  // streamed output writes (plain cached stores -> L3-buffered)
  const float4* tau4 = (const float4*)tau_col;   // 16 KB, L2-resident
  float4* orow4 = (float4*)(out_row + (size_t)i * N);
  float4* ocol4 = (float4*)(out_col + (size_t)i * N);
  #pragma unroll
  for (int s = 0; s < 16; ++s){
    float4 p;
    p.x = fmaxf(x4[s].x - tau, 0.0f);
    p.y = fmaxf(x4[s].y - tau, 0.0f);
    p.z = fmaxf(x4[s].z - tau, 0.0f);
    p.w = fmaxf(x4[s].w - tau, 0.0f);
    orow4[lane + s * 64] = p;

    float4 tt = tau4[lane + s * 64];
    float4 pc;
    pc.x = fmaxf(x4[s].x - tt.x, 0.0f);
    pc.y = fmaxf(x4[s].y - tt.y, 0.0f);
    pc.z = fmaxf(x4[s].z - tt.z, 0.0f);
    pc.w = fmaxf(x4[s].w - tt.w, 0.0f);
    ocol4[lane + s * 64] = pc;
  }

  // beta gather over candidates, filtered to the true support (v - tau > 0)
  float a0 = 0, a1 = 0, a2 = 0, a3 = 0;
  for (int l = 0; l < ns; ++l){
    float pp = sup_v[w][l] - tau;
    if (pp > 0.0f){
      const float* cr = colvecs + (size_t)sup_j[w][l] * DD;
      a0 += pp * cr[lane];        a1 += pp * cr[64 + lane];
      a2 += pp * cr[128 + lane];  a3 += pp * cr[192 + lane];
    }
  }
  float* be = beta + (size_t)i * DD;
  be[lane] = a0; be[64 + lane] = a1; be[128 + lane] = a2; be[192 + lane] = a3;
}

// ---------------------------------------------------------------------------
// G(x) = leaky_relu(x @ W + b); accumulate column sums for the means
// (verbatim round 7)
// ---------------------------------------------------------------------------
__global__ __launch_bounds__(256) void k_G(const float* __restrict__ beta,
      const float* __restrict__ alpha, const float* __restrict__ W,
      const float* __restrict__ bG, float* __restrict__ vsum){
  int t = threadIdx.x, side = blockIdx.y, r0 = blockIdx.x * 16;
  const float* src = side ? alpha : beta;
  __shared__ float sB[16 * 256];
  #pragma unroll
  for (int k = 0; k < 16; ++k) sB[k * 256 + t] = src[(size_t)(r0 + k) * 256 + t];
  __syncthreads();
  float acc[16];
  float bg = bG[t];
  #pragma unroll
  for (int r = 0; r < 16; ++r) acc[r] = bg;
  const float4* sB4 = (const float4*)sB;
  for (int d4 = 0; d4 < 64; ++d4){
    int d = d4 * 4;
    float w0 = W[(size_t)d * 256 + t];
    float w1 = W[(size_t)(d + 1) * 256 + t];
    float w2 = W[(size_t)(d + 2) * 256 + t];
    float w3 = W[(size_t)(d + 3) * 256 + t];
    #pragma unroll
    for (int r = 0; r < 16; ++r){
      float4 s = sB4[r * 64 + d4];
      acc[r] += s.x * w0 + s.y * w1 + s.z * w2 + s.w * w3;
    }
  }
  float s = 0.0f;
  #pragma unroll
  for (int r = 0; r < 16; ++r){ float u = acc[r]; s += (u > 0.0f) ? u : LEAKY * u; }
  atomicAdd(&vsum[side * 256 + t], s);
}

// ---------------------------------------------------------------------------
// FUSED k_final + k_fill: every block recomputes the cosine scalar from vsum
// (2 KB L2 read + ~40 VALU ops, negligible) and fills its slice of out0.
// Plain stores: pure write stream rides L2/L3.
// ---------------------------------------------------------------------------
__global__ __launch_bounds__(256) void k_fill(const float* __restrict__ vsum,
                                              float4* __restrict__ out0){
  const int t = threadIdx.x, w = t >> 6, lane = t & 63;
  __shared__ float rd[13];
  float v1 = vsum[t]       * (1.0f / 4096.0f);
  float v2 = vsum[256 + t] * (1.0f / 4096.0f);
  float d = v1 * v2, a = v1 * v1, b = v2 * v2;
  for (int off = 32; off; off >>= 1){
    d += __shfl_xor(d, off); a += __shfl_xor(a, off); b += __shfl_xor(b, off);
  }
  if (lane == 0){ rd[w] = d; rd[4 + w] = a; rd[8 + w] = b; }
  __syncthreads();
  if (t == 0){
    float dd = rd[0] + rd[1] + rd[2] + rd[3];
    float aa = rd[4] + rd[5] + rd[6] + rd[7];
    float bb = rd[8] + rd[9] + rd[10] + rd[11];
    rd[12] = 1.0f - dd / (sqrtf(aa) * sqrtf(bb) + 1e-8f);
  }
  __syncthreads();
  const float y = rd[12];
  const float4 f = make_float4(y, y, y, y);
  int idx = blockIdx.x * 256 + t;
  #pragma unroll
  for (int k = 0; k < 8; ++k)
    out0[idx + k * 524288] = f;
}

extern "C" void kernel_launch(void* const* d_in, const int* in_sizes, int n_in,
                              void* d_out, int out_size, void* d_ws, size_t ws_size,
                              hipStream_t stream){
  const float* rowv = (const float*)d_in[0];   // [4096,256]
  const float* colv = (const float*)d_in[1];   // [4096,256]
  const float* cost = (const float*)d_in[2];   // [4096,4096]
  const float* W    = (const float*)d_in[3];   // [256,256]
  const float* bG   = (const float*)d_in[4];   // [256]

  float* out0    = (float*)d_out;
  float* out_row = out0 + (size_t)N * N;
  float* out_col = out0 + 2 * (size_t)N * N;

  int*    cnt   = (int*)d_ws;
  float*  vsum  = (float*)d_ws + 4096;
  float*  tau   = (float*)d_ws + 4608;
  float*  beta  = (float*)d_ws + 8704;
  float*  alpha = (float*)d_ws + 8704 + 1048576;
  float2* candp = (float2*)((float*)d_ws + 8704 + 2 * 1048576);  // 16.8 MB pairs

  hipMemsetAsync(d_ws, 0, (size_t)4608 * 4, stream);   // cnt + vsum

  hipLaunchKernelGGL(k_cand,   dim3(64, 32), dim3(256), 0, stream, cost, cnt, candp);
  hipLaunchKernelGGL(k_coltau, dim3(1024),   dim3(256), 0, stream, cnt, candp, rowv, tau, alpha);
  hipLaunchKernelGGL(k_row,    dim3(1024),   dim3(256), 0, stream, cost, colv, tau, out_row, out_col, beta);
  hipLaunchKernelGGL(k_G,      dim3(256,2),  dim3(256), 0, stream, beta, alpha, W, bG, vsum);
  hipLaunchKernelGGL(k_fill,   dim3(2048),   dim3(256), 0, stream, vsum, (float4*)out0);
}